// Round 12
// baseline (1891.699 us; speedup 1.0000x reference)
//
#include <hip/hip_runtime.h>
#include <cmath>

#define NPTS  200000
#define KNBR  16
#define MROWS 3200000   // NPTS*KNBR
#define EPSB  1e-5f
#define H2LD  260       // h2t row stride in floats

__device__ __forceinline__ float gelu_f(float x) {
    return 0.5f * x * (1.0f + erff(x * 0.70710678118654752f));
}

// ---------------- pack p (12B) + f (16B) into one 32B record per point ----------------
__global__ __launch_bounds__(256) void k_pack(
    const float* __restrict__ p, const float4* __restrict__ f,
    float4* __restrict__ pk)
{
    int n = blockIdx.x * 256 + threadIdx.x;
    if (n < NPTS) {
        float4 a;
        a.x = p[n * 3 + 0]; a.y = p[n * 3 + 1]; a.z = p[n * 3 + 2]; a.w = 0.f;
        pk[2 * n]     = a;
        pk[2 * n + 1] = f[n];
    }
}

// ================= BIG-WORKSPACE PATH =================
// y1 dump layout (float4-native): per 64-row tile (1024 floats),
//   y1d[tile*1024 + (j>>2)*256 + lane*4 + (j&3)]
// -> writer stores 4x float4/row, readers load 4x dwordx4/row, all coalesced.
__global__ __launch_bounds__(256) void k_gy1(
    const float4* __restrict__ pk, const int* __restrict__ gidx,
    const float* __restrict__ w1, float* __restrict__ stats,
    float* __restrict__ y1d)
{
    __shared__ __align__(16) float w1s[112];
    __shared__ float red[4 * 32];
    for (int i = threadIdx.x; i < 112; i += 256) w1s[i] = w1[i];
    __syncthreads();
    const float4* w1v = (const float4*)w1s;   // [7][4]

    float acc[32];
#pragma unroll
    for (int c = 0; c < 32; c++) acc[c] = 0.f;

    int tid = threadIdx.x;
    int lr = tid & 63;
    int stride = gridDim.x * 256;
#pragma unroll 1
    for (int r = blockIdx.x * 256 + tid; r < MROWS; r += stride) {
        int n = r >> 4;
        int idx = gidx[r];
        float4 pa = pk[2 * idx];
        float4 fb = pk[2 * idx + 1];
        float4 pc = pk[2 * n];
        float x[7];
        x[0] = pa.x - pc.x; x[1] = pa.y - pc.y; x[2] = pa.z - pc.z;
        x[3] = fb.x; x[4] = fb.y; x[5] = fb.z; x[6] = fb.w;
        float* tb = y1d + (size_t)(r >> 6) * 1024;
#pragma unroll
        for (int j0 = 0; j0 < 16; j0 += 4) {
            float y0 = 0.f, y1 = 0.f, y2 = 0.f, y3 = 0.f;
#pragma unroll
            for (int i = 0; i < 7; i++) {
                float4 w = w1v[i * 4 + (j0 >> 2)];
                float xi = x[i];
                y0 = fmaf(xi, w.x, y0); y1 = fmaf(xi, w.y, y1);
                y2 = fmaf(xi, w.z, y2); y3 = fmaf(xi, w.w, y3);
            }
            ((float4*)(tb + (j0 >> 2) * 256))[lr] = make_float4(y0, y1, y2, y3);
            acc[j0 + 0] += y0; acc[16 + j0 + 0] += y0 * y0;
            acc[j0 + 1] += y1; acc[16 + j0 + 1] += y1 * y1;
            acc[j0 + 2] += y2; acc[16 + j0 + 2] += y2 * y2;
            acc[j0 + 3] += y3; acc[16 + j0 + 3] += y3 * y3;
        }
    }
    int lane = tid & 63, wv = tid >> 6;
#pragma unroll
    for (int c = 0; c < 32; c++) {
        float v = acc[c];
        v += __shfl_down(v, 32); v += __shfl_down(v, 16); v += __shfl_down(v, 8);
        v += __shfl_down(v, 4);  v += __shfl_down(v, 2);  v += __shfl_down(v, 1);
        if (lane == 0) red[wv * 32 + c] = v;
    }
    __syncthreads();
    for (int c = tid; c < 32; c += 256)
        atomicAdd(&stats[c], red[c] + red[32 + c] + red[64 + c] + red[96 + c]);
}

// BN1 finalize from y1 sums
__global__ void k_fin1b(const float* __restrict__ stats, const float* __restrict__ g,
                        const float* __restrict__ b, float* __restrict__ scsh)
{
    int j = threadIdx.x;
    if (j < 16) {
        const float invM = 1.0f / (float)MROWS;
        float m = stats[j] * invM;
        float v = stats[16 + j] * invM - m * m;
        float sc = g[j] * rsqrtf(v + EPSB);
        scsh[j] = sc;
        scsh[16 + j] = fmaf(-m, sc, b[j]);
    }
}

// load h1 (16) from the float4-tiled y1 dump for row r (lane lr)
__device__ __forceinline__ void load_h1(const float* __restrict__ y1d, int r, int lr,
                                        const float* sc1s, const float* sh1s,
                                        float* h1)
{
    const float* tb = y1d + (size_t)(r >> 6) * 1024;
#pragma unroll
    for (int g = 0; g < 4; g++) {
        float4 v = ((const float4*)(tb + g * 256))[lr];
        h1[4 * g + 0] = gelu_f(fmaf(v.x, sc1s[4 * g + 0], sh1s[4 * g + 0]));
        h1[4 * g + 1] = gelu_f(fmaf(v.y, sc1s[4 * g + 1], sh1s[4 * g + 1]));
        h1[4 * g + 2] = gelu_f(fmaf(v.z, sc1s[4 * g + 2], sh1s[4 * g + 2]));
        h1[4 * g + 3] = gelu_f(fmaf(v.w, sc1s[4 * g + 3], sh1s[4 * g + 3]));
    }
}

// ---------------- z-stats, HALF-channel pass (32 accumulators) ----------------
// z = h1 @ w2 for channels [HALF*16, HALF*16+16); accumulate z and z^2.
// launch_bounds(256,3): cap VGPR ~170 -> 3 waves/SIMD (r11: 216 VGPR -> 2).
template <int HALF>
__global__ __launch_bounds__(256, 3) void k_momZh(
    const float* __restrict__ y1d, const float* __restrict__ w2,
    const float* __restrict__ scsh1, float* __restrict__ stats)
{
    __shared__ __align__(16) float w2s[512];
    __shared__ float sc1s[16], sh1s[16];
    __shared__ float red[4 * 32];
    for (int i = threadIdx.x; i < 512; i += 256) w2s[i] = w2[i];
    if (threadIdx.x < 16) {
        sc1s[threadIdx.x] = scsh1[threadIdx.x];
        sh1s[threadIdx.x] = scsh1[16 + threadIdx.x];
    }
    __syncthreads();
    const float4* w2v = (const float4*)w2s;   // [16][8]

    float acc[32];
#pragma unroll
    for (int c = 0; c < 32; c++) acc[c] = 0.f;

    int tid = threadIdx.x;
    int lr = tid & 63;
    int stride = gridDim.x * 256;
#pragma unroll 1
    for (int r = blockIdx.x * 256 + tid; r < MROWS; r += stride) {
        float h1[16];
        load_h1(y1d, r, lr, sc1s, sh1s, h1);
#pragma unroll
        for (int j0 = 0; j0 < 16; j0 += 4) {
            float y0 = 0.f, y1 = 0.f, y2 = 0.f, y3 = 0.f;
#pragma unroll
            for (int i = 0; i < 16; i++) {
                float4 w = w2v[i * 8 + HALF * 4 + (j0 >> 2)];
                float hi = h1[i];
                y0 = fmaf(hi, w.x, y0); y1 = fmaf(hi, w.y, y1);
                y2 = fmaf(hi, w.z, y2); y3 = fmaf(hi, w.w, y3);
            }
            acc[j0 + 0] += y0; acc[16 + j0 + 0] += y0 * y0;
            acc[j0 + 1] += y1; acc[16 + j0 + 1] += y1 * y1;
            acc[j0 + 2] += y2; acc[16 + j0 + 2] += y2 * y2;
            acc[j0 + 3] += y3; acc[16 + j0 + 3] += y3 * y3;
        }
    }
    int lane = tid & 63, wv = tid >> 6;
#pragma unroll
    for (int c = 0; c < 32; c++) {
        float v = acc[c];
        v += __shfl_down(v, 32); v += __shfl_down(v, 16); v += __shfl_down(v, 8);
        v += __shfl_down(v, 4);  v += __shfl_down(v, 2);  v += __shfl_down(v, 1);
        if (lane == 0) red[wv * 32 + c] = v;
    }
    __syncthreads();
    // stats layout for k_finalize(H=32): stats[ch]=sum, stats[32+ch]=sumsq
    for (int c = tid; c < 32; c += 256) {
        float v = red[c] + red[32 + c] + red[64 + c] + red[96 + c];
        int ch = HALF * 16 + (c & 15);
        atomicAdd(&stats[(c < 16) ? ch : (32 + ch)], v);
    }
}

// direct BN finalize: scale/shift from sum/sumsq
__global__ void k_finalize(const float* __restrict__ stats, const float* __restrict__ g,
                           const float* __restrict__ b, float* __restrict__ scsh,
                           int H, float invM)
{
    int j = threadIdx.x;
    if (j < H) {
        float m = stats[j] * invM;
        float v = stats[H + j] * invM - m * m;
        float sc = g[j] * rsqrtf(v + EPSB);
        scsh[j] = sc;
        scsh[H + j] = fmaf(-m, sc, b[j]);
    }
}

// Two-phase pool kernel; phase A reads y1 as 4x float4; phase B i-outer with
// explicit component FMAs.
__global__ __launch_bounds__(256) void k_pool2y(
    const float* __restrict__ y1d,
    const float* __restrict__ w2, const float* __restrict__ w3,
    const float* __restrict__ scsh1, const float* __restrict__ scsh2,
    float* __restrict__ stats, float* __restrict__ pooled)
{
    __shared__ __align__(16) float w2s[512];
    __shared__ __align__(16) float w3s[2048];
    __shared__ __align__(16) float h2t[32 * H2LD];
    __shared__ float sc1s[16], sh1s[16], sc2s[32], sh2s[32];
    __shared__ float reds[256];
    __shared__ float redq[256];
    int tid = threadIdx.x;
    for (int i = tid; i < 512; i += 256) w2s[i] = w2[i];
    for (int i = tid; i < 2048; i += 256) w3s[i] = w3[i];
    if (tid < 16) { sc1s[tid] = scsh1[tid]; sh1s[tid] = scsh1[16 + tid]; }
    if (tid < 32) { sc2s[tid] = scsh2[tid]; sh2s[tid] = scsh2[32 + tid]; }
    __syncthreads();

    const float4* w2v = (const float4*)w2s;   // [16][8]
    const float4* w3v = (const float4*)w3s;   // [32][16]

    int lane = tid & 63;
    int pt = tid >> 4;
    int cc = tid & 15;

    float s0 = 0.f, s1 = 0.f, s2 = 0.f, s3 = 0.f;
    float q0 = 0.f, q1 = 0.f, q2 = 0.f, q3 = 0.f;

#pragma unroll 1
    for (int it = 0; it < 4; it++) {
        // ---------- phase A ----------
        int r = it * 800000 + blockIdx.x * 256 + tid;
        float h1[16];
        load_h1(y1d, r, lane, sc1s, sh1s, h1);
#pragma unroll
        for (int j0 = 0; j0 < 32; j0 += 4) {
            float y0 = 0.f, y1 = 0.f, y2 = 0.f, y3 = 0.f;
#pragma unroll
            for (int i = 0; i < 16; i++) {
                float4 w = w2v[i * 8 + (j0 >> 2)];
                float hi = h1[i];
                y0 = fmaf(hi, w.x, y0); y1 = fmaf(hi, w.y, y1);
                y2 = fmaf(hi, w.z, y2); y3 = fmaf(hi, w.w, y3);
            }
            h2t[(j0 + 0) * H2LD + tid] = gelu_f(fmaf(y0, sc2s[j0 + 0], sh2s[j0 + 0]));
            h2t[(j0 + 1) * H2LD + tid] = gelu_f(fmaf(y1, sc2s[j0 + 1], sh2s[j0 + 1]));
            h2t[(j0 + 2) * H2LD + tid] = gelu_f(fmaf(y2, sc2s[j0 + 2], sh2s[j0 + 2]));
            h2t[(j0 + 3) * H2LD + tid] = gelu_f(fmaf(y3, sc2s[j0 + 3], sh2s[j0 + 3]));
        }
        __syncthreads();

        // ---------- phase B: i-outer, a[16][4] tile, component FMAs ----------
        float a[16][4];
#pragma unroll
        for (int t = 0; t < 16; t++) {
            a[t][0] = 0.f; a[t][1] = 0.f; a[t][2] = 0.f; a[t][3] = 0.f;
        }
        int rb0 = pt << 4;
#define ACC4(t, hv) \
            a[t][0] = fmaf(hv, wf.x, a[t][0]); \
            a[t][1] = fmaf(hv, wf.y, a[t][1]); \
            a[t][2] = fmaf(hv, wf.z, a[t][2]); \
            a[t][3] = fmaf(hv, wf.w, a[t][3]);
#pragma unroll 8
        for (int i = 0; i < 32; i++) {
            float4 wf = w3v[i * 16 + cc];                 // read ONCE per i
            const float4* hp = (const float4*)&h2t[i * H2LD + rb0];
            float4 hA = hp[0];
            float4 hB = hp[1];
            float4 hC = hp[2];
            float4 hD = hp[3];
            ACC4(0,  hA.x) ACC4(1,  hA.y) ACC4(2,  hA.z) ACC4(3,  hA.w)
            ACC4(4,  hB.x) ACC4(5,  hB.y) ACC4(6,  hB.z) ACC4(7,  hB.w)
            ACC4(8,  hC.x) ACC4(9,  hC.y) ACC4(10, hC.z) ACC4(11, hC.w)
            ACC4(12, hD.x) ACC4(13, hD.y) ACC4(14, hD.z) ACC4(15, hD.w)
        }
#undef ACC4
        float m0 = -3.0e38f, m1 = -3.0e38f, m2 = -3.0e38f, m3 = -3.0e38f;
#pragma unroll
        for (int t = 0; t < 16; t++) {
            m0 = fmaxf(m0, a[t][0]);
            m1 = fmaxf(m1, a[t][1]);
            m2 = fmaxf(m2, a[t][2]);
            m3 = fmaxf(m3, a[t][3]);
        }
        int np = it * 50000 + blockIdx.x * 16 + pt;
        *(float4*)&pooled[(size_t)np * 64 + cc * 4] = make_float4(m0, m1, m2, m3);
        s0 += m0; q0 = fmaf(m0, m0, q0);
        s1 += m1; q1 = fmaf(m1, m1, q1);
        s2 += m2; q2 = fmaf(m2, m2, q2);
        s3 += m3; q3 = fmaf(m3, m3, q3);
        __syncthreads();
    }

    s0 += __shfl_down(s0, 32); s0 += __shfl_down(s0, 16);
    s1 += __shfl_down(s1, 32); s1 += __shfl_down(s1, 16);
    s2 += __shfl_down(s2, 32); s2 += __shfl_down(s2, 16);
    s3 += __shfl_down(s3, 32); s3 += __shfl_down(s3, 16);
    q0 += __shfl_down(q0, 32); q0 += __shfl_down(q0, 16);
    q1 += __shfl_down(q1, 32); q1 += __shfl_down(q1, 16);
    q2 += __shfl_down(q2, 32); q2 += __shfl_down(q2, 16);
    q3 += __shfl_down(q3, 32); q3 += __shfl_down(q3, 16);
    int wv = tid >> 6;
    if (lane < 16) {
        reds[wv * 64 + lane * 4 + 0] = s0;
        reds[wv * 64 + lane * 4 + 1] = s1;
        reds[wv * 64 + lane * 4 + 2] = s2;
        reds[wv * 64 + lane * 4 + 3] = s3;
        redq[wv * 64 + lane * 4 + 0] = q0;
        redq[wv * 64 + lane * 4 + 1] = q1;
        redq[wv * 64 + lane * 4 + 2] = q2;
        redq[wv * 64 + lane * 4 + 3] = q3;
    }
    __syncthreads();
    if (tid < 64) {
        atomicAdd(&stats[tid],
                  reds[tid] + reds[64 + tid] + reds[128 + tid] + reds[192 + tid]);
        atomicAdd(&stats[64 + tid],
                  redq[tid] + redq[64 + tid] + redq[128 + tid] + redq[192 + tid]);
    }
}

// ================= FALLBACK PATH (small workspace) =================
__global__ __launch_bounds__(256) void k_s1g(
    const float4* __restrict__ pk, const int* __restrict__ gidx,
    float* __restrict__ stats)
{
    __shared__ float red[4 * 35];
    float acc[35];
#pragma unroll
    for (int c = 0; c < 35; c++) acc[c] = 0.f;
    int stride = gridDim.x * 256;
#pragma unroll 1
    for (int r = blockIdx.x * 256 + threadIdx.x; r < MROWS; r += stride) {
        int n = r >> 4;
        int idx = gidx[r];
        float4 pa = pk[2 * idx];
        float4 fb = pk[2 * idx + 1];
        float4 pc = pk[2 * n];
        float x[7];
        x[0] = pa.x - pc.x; x[1] = pa.y - pc.y; x[2] = pa.z - pc.z;
        x[3] = fb.x; x[4] = fb.y; x[5] = fb.z; x[6] = fb.w;
#pragma unroll
        for (int i = 0; i < 7; i++) acc[i] += x[i];
        int t = 7;
#pragma unroll
        for (int i = 0; i < 7; i++)
#pragma unroll
            for (int l = i; l < 7; l++) { acc[t] = fmaf(x[i], x[l], acc[t]); t++; }
    }
    int lane = threadIdx.x & 63, wv = threadIdx.x >> 6;
#pragma unroll
    for (int c = 0; c < 35; c++) {
        float v = acc[c];
        v += __shfl_down(v, 32); v += __shfl_down(v, 16); v += __shfl_down(v, 8);
        v += __shfl_down(v, 4);  v += __shfl_down(v, 2);  v += __shfl_down(v, 1);
        if (lane == 0) red[wv * 35 + c] = v;
    }
    __syncthreads();
    for (int c = threadIdx.x; c < 35; c += 256)
        atomicAdd(&stats[c], red[c] + red[35 + c] + red[70 + c] + red[105 + c]);
}

__global__ void k_f1g(const float* __restrict__ stats, const float* __restrict__ w1,
                      const float* __restrict__ g, const float* __restrict__ b,
                      float* __restrict__ scsh)
{
    int j = threadIdx.x;
    if (j < 16) {
        const float invM = 1.0f / (float)MROWS;
        float w[7];
#pragma unroll
        for (int i = 0; i < 7; i++) w[i] = w1[i * 16 + j];
        float m = 0.f;
#pragma unroll
        for (int i = 0; i < 7; i++) m = fmaf(w[i], stats[i], m);
        m *= invM;
        float e2 = 0.f;
        int t = 7;
#pragma unroll
        for (int i = 0; i < 7; i++)
#pragma unroll
            for (int l = i; l < 7; l++) {
                float coeff = (i == l) ? 1.0f : 2.0f;
                e2 = fmaf(coeff * w[i] * w[l], stats[t], e2);
                t++;
            }
        e2 *= invM;
        float v = e2 - m * m;
        float sc = g[j] * rsqrtf(v + EPSB);
        scsh[j] = sc;
        scsh[16 + j] = fmaf(-m, sc, b[j]);
    }
}

// fallback z-stats, half-channel gather variant (32 accs)
template <int HALF>
__global__ __launch_bounds__(256) void k_s2h(
    const float4* __restrict__ pk, const int* __restrict__ gidx,
    const float* __restrict__ w1, const float* __restrict__ w2,
    const float* __restrict__ scsh1, float* __restrict__ stats)
{
    __shared__ __align__(16) float w1s[112];
    __shared__ __align__(16) float w2s[512];
    __shared__ float sc1s[16], sh1s[16];
    __shared__ float red[4 * 32];
    for (int i = threadIdx.x; i < 112; i += 256) w1s[i] = w1[i];
    for (int i = threadIdx.x; i < 512; i += 256) w2s[i] = w2[i];
    if (threadIdx.x < 16) {
        sc1s[threadIdx.x] = scsh1[threadIdx.x];
        sh1s[threadIdx.x] = scsh1[16 + threadIdx.x];
    }
    __syncthreads();
    const float4* w1v = (const float4*)w1s;
    const float4* w2v = (const float4*)w2s;

    float acc[32];
#pragma unroll
    for (int c = 0; c < 32; c++) acc[c] = 0.f;

    int stride = gridDim.x * 256;
#pragma unroll 1
    for (int r = blockIdx.x * 256 + threadIdx.x; r < MROWS; r += stride) {
        int n = r >> 4;
        int idx = gidx[r];
        float4 pa = pk[2 * idx];
        float4 fb = pk[2 * idx + 1];
        float4 pc = pk[2 * n];
        float x[7];
        x[0] = pa.x - pc.x; x[1] = pa.y - pc.y; x[2] = pa.z - pc.z;
        x[3] = fb.x; x[4] = fb.y; x[5] = fb.z; x[6] = fb.w;
        float h1[16];
#pragma unroll
        for (int j0 = 0; j0 < 16; j0 += 4) {
            float y0 = 0.f, y1 = 0.f, y2 = 0.f, y3 = 0.f;
#pragma unroll
            for (int i = 0; i < 7; i++) {
                float4 w = w1v[i * 4 + (j0 >> 2)];
                float xi = x[i];
                y0 = fmaf(xi, w.x, y0); y1 = fmaf(xi, w.y, y1);
                y2 = fmaf(xi, w.z, y2); y3 = fmaf(xi, w.w, y3);
            }
            h1[j0 + 0] = gelu_f(fmaf(y0, sc1s[j0 + 0], sh1s[j0 + 0]));
            h1[j0 + 1] = gelu_f(fmaf(y1, sc1s[j0 + 1], sh1s[j0 + 1]));
            h1[j0 + 2] = gelu_f(fmaf(y2, sc1s[j0 + 2], sh1s[j0 + 2]));
            h1[j0 + 3] = gelu_f(fmaf(y3, sc1s[j0 + 3], sh1s[j0 + 3]));
        }
#pragma unroll
        for (int j0 = 0; j0 < 16; j0 += 4) {
            float y0 = 0.f, y1 = 0.f, y2 = 0.f, y3 = 0.f;
#pragma unroll
            for (int i = 0; i < 16; i++) {
                float4 w = w2v[i * 8 + HALF * 4 + (j0 >> 2)];
                float hi = h1[i];
                y0 = fmaf(hi, w.x, y0); y1 = fmaf(hi, w.y, y1);
                y2 = fmaf(hi, w.z, y2); y3 = fmaf(hi, w.w, y3);
            }
            acc[j0 + 0] += y0; acc[16 + j0 + 0] += y0 * y0;
            acc[j0 + 1] += y1; acc[16 + j0 + 1] += y1 * y1;
            acc[j0 + 2] += y2; acc[16 + j0 + 2] += y2 * y2;
            acc[j0 + 3] += y3; acc[16 + j0 + 3] += y3 * y3;
        }
    }
    int lane = threadIdx.x & 63, wv = threadIdx.x >> 6;
#pragma unroll
    for (int c = 0; c < 32; c++) {
        float v = acc[c];
        v += __shfl_down(v, 32); v += __shfl_down(v, 16); v += __shfl_down(v, 8);
        v += __shfl_down(v, 4);  v += __shfl_down(v, 2);  v += __shfl_down(v, 1);
        if (lane == 0) red[wv * 32 + c] = v;
    }
    __syncthreads();
    for (int c = threadIdx.x; c < 32; c += 256) {
        float v = red[c] + red[32 + c] + red[64 + c] + red[96 + c];
        int ch = HALF * 16 + (c & 15);
        atomicAdd(&stats[(c < 16) ? ch : (32 + ch)], v);
    }
}

__global__ __launch_bounds__(256) void k_pool2g(
    const float* __restrict__ p, const float4* __restrict__ f,
    const int* __restrict__ gidx,
    const float* __restrict__ w1, const float* __restrict__ w2,
    const float* __restrict__ w3,
    const float* __restrict__ scsh1, const float* __restrict__ scsh2,
    float* __restrict__ stats, float* __restrict__ pooled)
{
    __shared__ __align__(16) float w1s[112];
    __shared__ __align__(16) float w2s[512];
    __shared__ __align__(16) float w3s[2048];
    __shared__ __align__(16) float h2t[32 * H2LD];
    __shared__ float sc1s[16], sh1s[16], sc2s[32], sh2s[32];
    __shared__ float reds[256];
    __shared__ float redq[256];
    int tid = threadIdx.x;
    for (int i = tid; i < 112; i += 256) w1s[i] = w1[i];
    for (int i = tid; i < 512; i += 256) w2s[i] = w2[i];
    for (int i = tid; i < 2048; i += 256) w3s[i] = w3[i];
    if (tid < 16) { sc1s[tid] = scsh1[tid]; sh1s[tid] = scsh1[16 + tid]; }
    if (tid < 32) { sc2s[tid] = scsh2[tid]; sh2s[tid] = scsh2[32 + tid]; }
    __syncthreads();

    const float4* w1v = (const float4*)w1s;
    const float4* w2v = (const float4*)w2s;
    const float4* w3v = (const float4*)w3s;

    int lane = tid & 63;
    int pt = tid >> 4;
    int cc = tid & 15;

    float s0 = 0.f, s1 = 0.f, s2 = 0.f, s3 = 0.f;
    float q0 = 0.f, q1 = 0.f, q2 = 0.f, q3 = 0.f;

#pragma unroll 1
    for (int it = 0; it < 4; it++) {
        int r = it * 800000 + blockIdx.x * 256 + tid;
        int n = r >> 4;
        int idx = gidx[r];
        float4 fv = f[idx];
        float x[7];
        x[0] = p[idx * 3 + 0] - p[n * 3 + 0];
        x[1] = p[idx * 3 + 1] - p[n * 3 + 1];
        x[2] = p[idx * 3 + 2] - p[n * 3 + 2];
        x[3] = fv.x; x[4] = fv.y; x[5] = fv.z; x[6] = fv.w;

        float h1[16];
#pragma unroll
        for (int j0 = 0; j0 < 16; j0 += 4) {
            float y0 = 0.f, y1 = 0.f, y2 = 0.f, y3 = 0.f;
#pragma unroll
            for (int i = 0; i < 7; i++) {
                float4 w = w1v[i * 4 + (j0 >> 2)];
                float xi = x[i];
                y0 = fmaf(xi, w.x, y0); y1 = fmaf(xi, w.y, y1);
                y2 = fmaf(xi, w.z, y2); y3 = fmaf(xi, w.w, y3);
            }
            h1[j0 + 0] = gelu_f(fmaf(y0, sc1s[j0 + 0], sh1s[j0 + 0]));
            h1[j0 + 1] = gelu_f(fmaf(y1, sc1s[j0 + 1], sh1s[j0 + 1]));
            h1[j0 + 2] = gelu_f(fmaf(y2, sc1s[j0 + 2], sh1s[j0 + 2]));
            h1[j0 + 3] = gelu_f(fmaf(y3, sc1s[j0 + 3], sh1s[j0 + 3]));
        }
#pragma unroll
        for (int j0 = 0; j0 < 32; j0 += 4) {
            float y0 = 0.f, y1 = 0.f, y2 = 0.f, y3 = 0.f;
#pragma unroll
            for (int i = 0; i < 16; i++) {
                float4 w = w2v[i * 8 + (j0 >> 2)];
                float hi = h1[i];
                y0 = fmaf(hi, w.x, y0); y1 = fmaf(hi, w.y, y1);
                y2 = fmaf(hi, w.z, y2); y3 = fmaf(hi, w.w, y3);
            }
            h2t[(j0 + 0) * H2LD + tid] = gelu_f(fmaf(y0, sc2s[j0 + 0], sh2s[j0 + 0]));
            h2t[(j0 + 1) * H2LD + tid] = gelu_f(fmaf(y1, sc2s[j0 + 1], sh2s[j0 + 1]));
            h2t[(j0 + 2) * H2LD + tid] = gelu_f(fmaf(y2, sc2s[j0 + 2], sh2s[j0 + 2]));
            h2t[(j0 + 3) * H2LD + tid] = gelu_f(fmaf(y3, sc2s[j0 + 3], sh2s[j0 + 3]));
        }
        __syncthreads();

        float a[16][4];
#pragma unroll
        for (int t = 0; t < 16; t++) {
            a[t][0] = 0.f; a[t][1] = 0.f; a[t][2] = 0.f; a[t][3] = 0.f;
        }
        int rb0 = pt << 4;
#define ACC4(t, hv) \
            a[t][0] = fmaf(hv, wf.x, a[t][0]); \
            a[t][1] = fmaf(hv, wf.y, a[t][1]); \
            a[t][2] = fmaf(hv, wf.z, a[t][2]); \
            a[t][3] = fmaf(hv, wf.w, a[t][3]);
#pragma unroll 8
        for (int i = 0; i < 32; i++) {
            float4 wf = w3v[i * 16 + cc];
            const float4* hp = (const float4*)&h2t[i * H2LD + rb0];
            float4 hA = hp[0];
            float4 hB = hp[1];
            float4 hC = hp[2];
            float4 hD = hp[3];
            ACC4(0,  hA.x) ACC4(1,  hA.y) ACC4(2,  hA.z) ACC4(3,  hA.w)
            ACC4(4,  hB.x) ACC4(5,  hB.y) ACC4(6,  hB.z) ACC4(7,  hB.w)
            ACC4(8,  hC.x) ACC4(9,  hC.y) ACC4(10, hC.z) ACC4(11, hC.w)
            ACC4(12, hD.x) ACC4(13, hD.y) ACC4(14, hD.z) ACC4(15, hD.w)
        }
#undef ACC4
        float m0 = -3.0e38f, m1 = -3.0e38f, m2 = -3.0e38f, m3 = -3.0e38f;
#pragma unroll
        for (int t = 0; t < 16; t++) {
            m0 = fmaxf(m0, a[t][0]);
            m1 = fmaxf(m1, a[t][1]);
            m2 = fmaxf(m2, a[t][2]);
            m3 = fmaxf(m3, a[t][3]);
        }
        int np = it * 50000 + blockIdx.x * 16 + pt;
        *(float4*)&pooled[(size_t)np * 64 + cc * 4] = make_float4(m0, m1, m2, m3);
        s0 += m0; q0 = fmaf(m0, m0, q0);
        s1 += m1; q1 = fmaf(m1, m1, q1);
        s2 += m2; q2 = fmaf(m2, m2, q2);
        s3 += m3; q3 = fmaf(m3, m3, q3);
        __syncthreads();
    }

    s0 += __shfl_down(s0, 32); s0 += __shfl_down(s0, 16);
    s1 += __shfl_down(s1, 32); s1 += __shfl_down(s1, 16);
    s2 += __shfl_down(s2, 32); s2 += __shfl_down(s2, 16);
    s3 += __shfl_down(s3, 32); s3 += __shfl_down(s3, 16);
    q0 += __shfl_down(q0, 32); q0 += __shfl_down(q0, 16);
    q1 += __shfl_down(q1, 32); q1 += __shfl_down(q1, 16);
    q2 += __shfl_down(q2, 32); q2 += __shfl_down(q2, 16);
    q3 += __shfl_down(q3, 32); q3 += __shfl_down(q3, 16);
    int wv = tid >> 6;
    if (lane < 16) {
        reds[wv * 64 + lane * 4 + 0] = s0;
        reds[wv * 64 + lane * 4 + 1] = s1;
        reds[wv * 64 + lane * 4 + 2] = s2;
        reds[wv * 64 + lane * 4 + 3] = s3;
        redq[wv * 64 + lane * 4 + 0] = q0;
        redq[wv * 64 + lane * 4 + 1] = q1;
        redq[wv * 64 + lane * 4 + 2] = q2;
        redq[wv * 64 + lane * 4 + 3] = q3;
    }
    __syncthreads();
    if (tid < 64) {
        atomicAdd(&stats[tid],
                  reds[tid] + reds[64 + tid] + reds[128 + tid] + reds[192 + tid]);
        atomicAdd(&stats[64 + tid],
                  redq[tid] + redq[64 + tid] + redq[128 + tid] + redq[192 + tid]);
    }
}

// double-BN collapse
__global__ void k_fin3(const float* __restrict__ stats,
                       const float* __restrict__ g_nbr, const float* __restrict__ g_post,
                       const float* __restrict__ b_post, float* __restrict__ scsh)
{
    int j = threadIdx.x;
    if (j < 64) {
        float m = stats[j] * (1.0f / NPTS);
        float v = stats[64 + j] * (1.0f / NPTS) - m * m;
        float a1 = g_nbr[j] * rsqrtf(v + EPSB);
        float s3 = g_post[j] * a1 * rsqrtf(fmaf(a1 * a1, v, EPSB));
        scsh[j] = s3;
        scsh[64 + j] = fmaf(-m, s3, b_post[j]);
    }
}

// head: (N x 64) @ (64 x 256)
__global__ __launch_bounds__(256) void k_head(
    const float* __restrict__ pooled, const float* __restrict__ scsh3,
    const float* __restrict__ wpost, float* __restrict__ out)
{
    __shared__ float rowbuf[512];
    __shared__ float s3s[64], c3s[64];
    int tid = threadIdx.x;
    if (tid < 64) { s3s[tid] = scsh3[tid]; c3s[tid] = scsh3[64 + tid]; }
    float wcol[64];
#pragma unroll
    for (int j = 0; j < 64; j++) wcol[j] = wpost[j * 256 + tid];
    __syncthreads();

    const int nchunks = NPTS / 8;  // 25000
    for (int c = blockIdx.x; c < nchunks; c += gridDim.x) {
        int n0 = c * 8;
#pragma unroll
        for (int t = tid; t < 512; t += 256) {
            int rr = t >> 6, j = t & 63;
            rowbuf[t] = fmaf(pooled[(size_t)(n0 + rr) * 64 + j], s3s[j], c3s[j]);
        }
        __syncthreads();
#pragma unroll
        for (int rr = 0; rr < 8; rr++) {
            float acc = 0.f;
#pragma unroll
            for (int j = 0; j < 64; j++) acc = fmaf(rowbuf[rr * 64 + j], wcol[j], acc);
            out[(size_t)(n0 + rr) * 256 + tid] = acc;
        }
        __syncthreads();
    }
}

extern "C" void kernel_launch(void* const* d_in, const int* in_sizes, int n_in,
                              void* d_out, int out_size, void* d_ws, size_t ws_size,
                              hipStream_t stream)
{
    const float*  p    = (const float*)d_in[0];
    const float4* f    = (const float4*)d_in[1];
    const int*    gidx = (const int*)d_in[2];
    const float*  w1   = (const float*)d_in[3];
    const float*  g1   = (const float*)d_in[4];
    const float*  b1   = (const float*)d_in[5];
    const float*  w2   = (const float*)d_in[6];
    const float*  g2   = (const float*)d_in[7];
    const float*  b2   = (const float*)d_in[8];
    const float*  w3   = (const float*)d_in[9];
    const float*  gn   = (const float*)d_in[10];
    // d_in[11] = b_nbr: cancels exactly in the collapsed double-BN
    const float*  gp   = (const float*)d_in[12];
    const float*  bp   = (const float*)d_in[13];
    const float*  wp   = (const float*)d_in[14];
    float* out = (float*)d_out;
    float* ws  = (float*)d_ws;

    float* stats1 = ws;          // 35 floats max
    float* scsh1  = ws + 40;     // 32
    float* stats2 = ws + 80;     // 64 floats (sum32 + sumsq32)
    float* scsh2  = ws + 240;    // 64
    float* stats3 = ws + 304;    // 128
    float* scsh3  = ws + 432;    // 128
    float* pooled = ws + 1024;               // 12.8M floats (51.2 MB)
    float4* pk    = (float4*)(ws + 1024);    // aliases pooled (dead before pool writes)
    float* y1d    = ws + 1024 + 12800000;    // 51.2M floats (204.8 MB)

    const size_t need = ((size_t)1024 + 12800000 + 51200000) * 4;

    hipMemsetAsync(d_ws, 0, 2048, stream);
    k_pack<<<(NPTS + 255) / 256, 256, 0, stream>>>(p, f, pk);

    if (ws_size >= need) {
        k_gy1<<<2048, 256, 0, stream>>>(pk, gidx, w1, stats1, y1d);
        k_fin1b<<<1, 64, 0, stream>>>(stats1, g1, b1, scsh1);
        k_momZh<0><<<2048, 256, 0, stream>>>(y1d, w2, scsh1, stats2);
        k_momZh<1><<<2048, 256, 0, stream>>>(y1d, w2, scsh1, stats2);
        k_finalize<<<1, 64, 0, stream>>>(stats2, g2, b2, scsh2, 32, 1.0f / (float)MROWS);
        k_pool2y<<<3125, 256, 0, stream>>>(y1d, w2, w3, scsh1, scsh2, stats3, pooled);
    } else {
        k_s1g<<<2048, 256, 0, stream>>>(pk, gidx, stats1);
        k_f1g<<<1, 64, 0, stream>>>(stats1, w1, g1, b1, scsh1);
        k_s2h<0><<<2048, 256, 0, stream>>>(pk, gidx, w1, w2, scsh1, stats2);
        k_s2h<1><<<2048, 256, 0, stream>>>(pk, gidx, w1, w2, scsh1, stats2);
        k_finalize<<<1, 64, 0, stream>>>(stats2, g2, b2, scsh2, 32, 1.0f / (float)MROWS);
        k_pool2g<<<3125, 256, 0, stream>>>(p, f, gidx, w1, w2, w3, scsh1, scsh2, stats3, pooled);
    }
    k_fin3<<<1, 64, 0, stream>>>(stats3, gn, gp, bp, scsh3);
    k_head<<<1024, 256, 0, stream>>>(pooled, scsh3, wp, out);
}

// Round 13
// 1303.252 us; speedup vs baseline: 1.4515x; 1.4515x over previous
//
#include <hip/hip_runtime.h>
#include <cmath>

#define NPTS  200000
#define KNBR  16
#define MROWS 3200000   // NPTS*KNBR
#define EPSB  1e-5f
#define H2LD  260       // h2t row stride in floats

__device__ __forceinline__ float gelu_f(float x) {
    return 0.5f * x * (1.0f + erff(x * 0.70710678118654752f));
}

// ---------------- pack p (12B) + f (16B) into one 32B record per point ----------------
__global__ __launch_bounds__(256) void k_pack(
    const float* __restrict__ p, const float4* __restrict__ f,
    float4* __restrict__ pk)
{
    int n = blockIdx.x * 256 + threadIdx.x;
    if (n < NPTS) {
        float4 a;
        a.x = p[n * 3 + 0]; a.y = p[n * 3 + 1]; a.z = p[n * 3 + 2]; a.w = 0.f;
        pk[2 * n]     = a;
        pk[2 * n + 1] = f[n];
    }
}

// ================= BIG-WORKSPACE PATH =================
// y1 dump layout (float4-native): per 64-row tile (1024 floats),
//   y1d[tile*1024 + (j>>2)*256 + lane*4 + (j&3)]
// -> writer stores 4x float4/row, readers load 4x dwordx4/row, all coalesced.
__global__ __launch_bounds__(256) void k_gy1(
    const float4* __restrict__ pk, const int* __restrict__ gidx,
    const float* __restrict__ w1, float* __restrict__ stats,
    float* __restrict__ y1d)
{
    __shared__ __align__(16) float w1s[112];
    __shared__ float red[4 * 32];
    for (int i = threadIdx.x; i < 112; i += 256) w1s[i] = w1[i];
    __syncthreads();
    const float4* w1v = (const float4*)w1s;   // [7][4]

    float acc[32];
#pragma unroll
    for (int c = 0; c < 32; c++) acc[c] = 0.f;

    int tid = threadIdx.x;
    int lr = tid & 63;
    int stride = gridDim.x * 256;
#pragma unroll 1
    for (int r = blockIdx.x * 256 + tid; r < MROWS; r += stride) {
        int n = r >> 4;
        int idx = gidx[r];
        float4 pa = pk[2 * idx];
        float4 fb = pk[2 * idx + 1];
        float4 pc = pk[2 * n];
        float x[7];
        x[0] = pa.x - pc.x; x[1] = pa.y - pc.y; x[2] = pa.z - pc.z;
        x[3] = fb.x; x[4] = fb.y; x[5] = fb.z; x[6] = fb.w;
        float* tb = y1d + (size_t)(r >> 6) * 1024;
#pragma unroll
        for (int j0 = 0; j0 < 16; j0 += 4) {
            float y0 = 0.f, y1 = 0.f, y2 = 0.f, y3 = 0.f;
#pragma unroll
            for (int i = 0; i < 7; i++) {
                float4 w = w1v[i * 4 + (j0 >> 2)];
                float xi = x[i];
                y0 = fmaf(xi, w.x, y0); y1 = fmaf(xi, w.y, y1);
                y2 = fmaf(xi, w.z, y2); y3 = fmaf(xi, w.w, y3);
            }
            ((float4*)(tb + (j0 >> 2) * 256))[lr] = make_float4(y0, y1, y2, y3);
            acc[j0 + 0] += y0; acc[16 + j0 + 0] += y0 * y0;
            acc[j0 + 1] += y1; acc[16 + j0 + 1] += y1 * y1;
            acc[j0 + 2] += y2; acc[16 + j0 + 2] += y2 * y2;
            acc[j0 + 3] += y3; acc[16 + j0 + 3] += y3 * y3;
        }
    }
    int lane = tid & 63, wv = tid >> 6;
#pragma unroll
    for (int c = 0; c < 32; c++) {
        float v = acc[c];
        v += __shfl_down(v, 32); v += __shfl_down(v, 16); v += __shfl_down(v, 8);
        v += __shfl_down(v, 4);  v += __shfl_down(v, 2);  v += __shfl_down(v, 1);
        if (lane == 0) red[wv * 32 + c] = v;
    }
    __syncthreads();
    for (int c = tid; c < 32; c += 256)
        atomicAdd(&stats[c], red[c] + red[32 + c] + red[64 + c] + red[96 + c]);
}

// BN1 finalize from y1 sums
__global__ void k_fin1b(const float* __restrict__ stats, const float* __restrict__ g,
                        const float* __restrict__ b, float* __restrict__ scsh)
{
    int j = threadIdx.x;
    if (j < 16) {
        const float invM = 1.0f / (float)MROWS;
        float m = stats[j] * invM;
        float v = stats[16 + j] * invM - m * m;
        float sc = g[j] * rsqrtf(v + EPSB);
        scsh[j] = sc;
        scsh[16 + j] = fmaf(-m, sc, b[j]);
    }
}

// load h1 (16) from the float4-tiled y1 dump for row r (lane lr)
__device__ __forceinline__ void load_h1(const float* __restrict__ y1d, int r, int lr,
                                        const float* sc1s, const float* sh1s,
                                        float* h1)
{
    const float* tb = y1d + (size_t)(r >> 6) * 1024;
#pragma unroll
    for (int g = 0; g < 4; g++) {
        float4 v = ((const float4*)(tb + g * 256))[lr];
        h1[4 * g + 0] = gelu_f(fmaf(v.x, sc1s[4 * g + 0], sh1s[4 * g + 0]));
        h1[4 * g + 1] = gelu_f(fmaf(v.y, sc1s[4 * g + 1], sh1s[4 * g + 1]));
        h1[4 * g + 2] = gelu_f(fmaf(v.z, sc1s[4 * g + 2], sh1s[4 * g + 2]));
        h1[4 * g + 3] = gelu_f(fmaf(v.w, sc1s[4 * g + 3], sh1s[4 * g + 3]));
    }
}

// ---------------- z-stats, HALF-channel pass, TWO rows per thread ----------------
// z = h1 @ w2 for channels [HALF*16, HALF*16+16); accumulate z and z^2 (32 accs).
// NO launch_bounds clamp (r12: (256,3) forced VGPR 84 + GBs of scratch traffic;
// r3: (256,4) same disease). Two rows/thread: 8 float4 loads in flight, 2x ILP.
// Grid 3125: rows {it*1.6M + b*256 + t, +800000} x it in {0,1} == all 3.2M rows.
template <int HALF>
__global__ __launch_bounds__(256) void k_momZh(
    const float* __restrict__ y1d, const float* __restrict__ w2,
    const float* __restrict__ scsh1, float* __restrict__ stats)
{
    __shared__ __align__(16) float w2s[512];
    __shared__ float sc1s[16], sh1s[16];
    __shared__ float red[4 * 32];
    for (int i = threadIdx.x; i < 512; i += 256) w2s[i] = w2[i];
    if (threadIdx.x < 16) {
        sc1s[threadIdx.x] = scsh1[threadIdx.x];
        sh1s[threadIdx.x] = scsh1[16 + threadIdx.x];
    }
    __syncthreads();
    const float4* w2v = (const float4*)w2s;   // [16][8]

    float acc[32];
#pragma unroll
    for (int c = 0; c < 32; c++) acc[c] = 0.f;

    int tid = threadIdx.x;
    int lr = tid & 63;
#pragma unroll 1
    for (int it = 0; it < 2; it++) {
        int rA = it * 1600000 + blockIdx.x * 256 + tid;
        int rB = rA + 800000;
        float h1A[16], h1B[16];
        load_h1(y1d, rA, lr, sc1s, sh1s, h1A);
        load_h1(y1d, rB, lr, sc1s, sh1s, h1B);
#pragma unroll
        for (int j0 = 0; j0 < 16; j0 += 4) {
            float a0 = 0.f, a1 = 0.f, a2 = 0.f, a3 = 0.f;
            float b0 = 0.f, b1 = 0.f, b2 = 0.f, b3 = 0.f;
#pragma unroll
            for (int i = 0; i < 16; i++) {
                float4 w = w2v[i * 8 + HALF * 4 + (j0 >> 2)];
                float ha = h1A[i], hb = h1B[i];
                a0 = fmaf(ha, w.x, a0); a1 = fmaf(ha, w.y, a1);
                a2 = fmaf(ha, w.z, a2); a3 = fmaf(ha, w.w, a3);
                b0 = fmaf(hb, w.x, b0); b1 = fmaf(hb, w.y, b1);
                b2 = fmaf(hb, w.z, b2); b3 = fmaf(hb, w.w, b3);
            }
            acc[j0 + 0] += a0 + b0;
            acc[16 + j0 + 0] += fmaf(a0, a0, b0 * b0);
            acc[j0 + 1] += a1 + b1;
            acc[16 + j0 + 1] += fmaf(a1, a1, b1 * b1);
            acc[j0 + 2] += a2 + b2;
            acc[16 + j0 + 2] += fmaf(a2, a2, b2 * b2);
            acc[j0 + 3] += a3 + b3;
            acc[16 + j0 + 3] += fmaf(a3, a3, b3 * b3);
        }
    }
    int lane = tid & 63, wv = tid >> 6;
#pragma unroll
    for (int c = 0; c < 32; c++) {
        float v = acc[c];
        v += __shfl_down(v, 32); v += __shfl_down(v, 16); v += __shfl_down(v, 8);
        v += __shfl_down(v, 4);  v += __shfl_down(v, 2);  v += __shfl_down(v, 1);
        if (lane == 0) red[wv * 32 + c] = v;
    }
    __syncthreads();
    // stats layout for k_finalize(H=32): stats[ch]=sum, stats[32+ch]=sumsq
    for (int c = tid; c < 32; c += 256) {
        float v = red[c] + red[32 + c] + red[64 + c] + red[96 + c];
        int ch = HALF * 16 + (c & 15);
        atomicAdd(&stats[(c < 16) ? ch : (32 + ch)], v);
    }
}

// direct BN finalize: scale/shift from sum/sumsq
__global__ void k_finalize(const float* __restrict__ stats, const float* __restrict__ g,
                           const float* __restrict__ b, float* __restrict__ scsh,
                           int H, float invM)
{
    int j = threadIdx.x;
    if (j < H) {
        float m = stats[j] * invM;
        float v = stats[H + j] * invM - m * m;
        float sc = g[j] * rsqrtf(v + EPSB);
        scsh[j] = sc;
        scsh[H + j] = fmaf(-m, sc, b[j]);
    }
}

// Two-phase pool kernel; phase A reads y1 as 4x float4; phase B i-outer with
// explicit component FMAs.
__global__ __launch_bounds__(256) void k_pool2y(
    const float* __restrict__ y1d,
    const float* __restrict__ w2, const float* __restrict__ w3,
    const float* __restrict__ scsh1, const float* __restrict__ scsh2,
    float* __restrict__ stats, float* __restrict__ pooled)
{
    __shared__ __align__(16) float w2s[512];
    __shared__ __align__(16) float w3s[2048];
    __shared__ __align__(16) float h2t[32 * H2LD];
    __shared__ float sc1s[16], sh1s[16], sc2s[32], sh2s[32];
    __shared__ float reds[256];
    __shared__ float redq[256];
    int tid = threadIdx.x;
    for (int i = tid; i < 512; i += 256) w2s[i] = w2[i];
    for (int i = tid; i < 2048; i += 256) w3s[i] = w3[i];
    if (tid < 16) { sc1s[tid] = scsh1[tid]; sh1s[tid] = scsh1[16 + tid]; }
    if (tid < 32) { sc2s[tid] = scsh2[tid]; sh2s[tid] = scsh2[32 + tid]; }
    __syncthreads();

    const float4* w2v = (const float4*)w2s;   // [16][8]
    const float4* w3v = (const float4*)w3s;   // [32][16]

    int lane = tid & 63;
    int pt = tid >> 4;
    int cc = tid & 15;

    float s0 = 0.f, s1 = 0.f, s2 = 0.f, s3 = 0.f;
    float q0 = 0.f, q1 = 0.f, q2 = 0.f, q3 = 0.f;

#pragma unroll 1
    for (int it = 0; it < 4; it++) {
        // ---------- phase A ----------
        int r = it * 800000 + blockIdx.x * 256 + tid;
        float h1[16];
        load_h1(y1d, r, lane, sc1s, sh1s, h1);
#pragma unroll
        for (int j0 = 0; j0 < 32; j0 += 4) {
            float y0 = 0.f, y1 = 0.f, y2 = 0.f, y3 = 0.f;
#pragma unroll
            for (int i = 0; i < 16; i++) {
                float4 w = w2v[i * 8 + (j0 >> 2)];
                float hi = h1[i];
                y0 = fmaf(hi, w.x, y0); y1 = fmaf(hi, w.y, y1);
                y2 = fmaf(hi, w.z, y2); y3 = fmaf(hi, w.w, y3);
            }
            h2t[(j0 + 0) * H2LD + tid] = gelu_f(fmaf(y0, sc2s[j0 + 0], sh2s[j0 + 0]));
            h2t[(j0 + 1) * H2LD + tid] = gelu_f(fmaf(y1, sc2s[j0 + 1], sh2s[j0 + 1]));
            h2t[(j0 + 2) * H2LD + tid] = gelu_f(fmaf(y2, sc2s[j0 + 2], sh2s[j0 + 2]));
            h2t[(j0 + 3) * H2LD + tid] = gelu_f(fmaf(y3, sc2s[j0 + 3], sh2s[j0 + 3]));
        }
        __syncthreads();

        // ---------- phase B: i-outer, a[16][4] tile, component FMAs ----------
        float a[16][4];
#pragma unroll
        for (int t = 0; t < 16; t++) {
            a[t][0] = 0.f; a[t][1] = 0.f; a[t][2] = 0.f; a[t][3] = 0.f;
        }
        int rb0 = pt << 4;
#define ACC4(t, hv) \
            a[t][0] = fmaf(hv, wf.x, a[t][0]); \
            a[t][1] = fmaf(hv, wf.y, a[t][1]); \
            a[t][2] = fmaf(hv, wf.z, a[t][2]); \
            a[t][3] = fmaf(hv, wf.w, a[t][3]);
#pragma unroll 8
        for (int i = 0; i < 32; i++) {
            float4 wf = w3v[i * 16 + cc];                 // read ONCE per i
            const float4* hp = (const float4*)&h2t[i * H2LD + rb0];
            float4 hA = hp[0];
            float4 hB = hp[1];
            float4 hC = hp[2];
            float4 hD = hp[3];
            ACC4(0,  hA.x) ACC4(1,  hA.y) ACC4(2,  hA.z) ACC4(3,  hA.w)
            ACC4(4,  hB.x) ACC4(5,  hB.y) ACC4(6,  hB.z) ACC4(7,  hB.w)
            ACC4(8,  hC.x) ACC4(9,  hC.y) ACC4(10, hC.z) ACC4(11, hC.w)
            ACC4(12, hD.x) ACC4(13, hD.y) ACC4(14, hD.z) ACC4(15, hD.w)
        }
#undef ACC4
        float m0 = -3.0e38f, m1 = -3.0e38f, m2 = -3.0e38f, m3 = -3.0e38f;
#pragma unroll
        for (int t = 0; t < 16; t++) {
            m0 = fmaxf(m0, a[t][0]);
            m1 = fmaxf(m1, a[t][1]);
            m2 = fmaxf(m2, a[t][2]);
            m3 = fmaxf(m3, a[t][3]);
        }
        int np = it * 50000 + blockIdx.x * 16 + pt;
        *(float4*)&pooled[(size_t)np * 64 + cc * 4] = make_float4(m0, m1, m2, m3);
        s0 += m0; q0 = fmaf(m0, m0, q0);
        s1 += m1; q1 = fmaf(m1, m1, q1);
        s2 += m2; q2 = fmaf(m2, m2, q2);
        s3 += m3; q3 = fmaf(m3, m3, q3);
        __syncthreads();
    }

    s0 += __shfl_down(s0, 32); s0 += __shfl_down(s0, 16);
    s1 += __shfl_down(s1, 32); s1 += __shfl_down(s1, 16);
    s2 += __shfl_down(s2, 32); s2 += __shfl_down(s2, 16);
    s3 += __shfl_down(s3, 32); s3 += __shfl_down(s3, 16);
    q0 += __shfl_down(q0, 32); q0 += __shfl_down(q0, 16);
    q1 += __shfl_down(q1, 32); q1 += __shfl_down(q1, 16);
    q2 += __shfl_down(q2, 32); q2 += __shfl_down(q2, 16);
    q3 += __shfl_down(q3, 32); q3 += __shfl_down(q3, 16);
    int wv = tid >> 6;
    if (lane < 16) {
        reds[wv * 64 + lane * 4 + 0] = s0;
        reds[wv * 64 + lane * 4 + 1] = s1;
        reds[wv * 64 + lane * 4 + 2] = s2;
        reds[wv * 64 + lane * 4 + 3] = s3;
        redq[wv * 64 + lane * 4 + 0] = q0;
        redq[wv * 64 + lane * 4 + 1] = q1;
        redq[wv * 64 + lane * 4 + 2] = q2;
        redq[wv * 64 + lane * 4 + 3] = q3;
    }
    __syncthreads();
    if (tid < 64) {
        atomicAdd(&stats[tid],
                  reds[tid] + reds[64 + tid] + reds[128 + tid] + reds[192 + tid]);
        atomicAdd(&stats[64 + tid],
                  redq[tid] + redq[64 + tid] + redq[128 + tid] + redq[192 + tid]);
    }
}

// ================= FALLBACK PATH (small workspace) =================
__global__ __launch_bounds__(256) void k_s1g(
    const float4* __restrict__ pk, const int* __restrict__ gidx,
    float* __restrict__ stats)
{
    __shared__ float red[4 * 35];
    float acc[35];
#pragma unroll
    for (int c = 0; c < 35; c++) acc[c] = 0.f;
    int stride = gridDim.x * 256;
#pragma unroll 1
    for (int r = blockIdx.x * 256 + threadIdx.x; r < MROWS; r += stride) {
        int n = r >> 4;
        int idx = gidx[r];
        float4 pa = pk[2 * idx];
        float4 fb = pk[2 * idx + 1];
        float4 pc = pk[2 * n];
        float x[7];
        x[0] = pa.x - pc.x; x[1] = pa.y - pc.y; x[2] = pa.z - pc.z;
        x[3] = fb.x; x[4] = fb.y; x[5] = fb.z; x[6] = fb.w;
#pragma unroll
        for (int i = 0; i < 7; i++) acc[i] += x[i];
        int t = 7;
#pragma unroll
        for (int i = 0; i < 7; i++)
#pragma unroll
            for (int l = i; l < 7; l++) { acc[t] = fmaf(x[i], x[l], acc[t]); t++; }
    }
    int lane = threadIdx.x & 63, wv = threadIdx.x >> 6;
#pragma unroll
    for (int c = 0; c < 35; c++) {
        float v = acc[c];
        v += __shfl_down(v, 32); v += __shfl_down(v, 16); v += __shfl_down(v, 8);
        v += __shfl_down(v, 4);  v += __shfl_down(v, 2);  v += __shfl_down(v, 1);
        if (lane == 0) red[wv * 35 + c] = v;
    }
    __syncthreads();
    for (int c = threadIdx.x; c < 35; c += 256)
        atomicAdd(&stats[c], red[c] + red[35 + c] + red[70 + c] + red[105 + c]);
}

__global__ void k_f1g(const float* __restrict__ stats, const float* __restrict__ w1,
                      const float* __restrict__ g, const float* __restrict__ b,
                      float* __restrict__ scsh)
{
    int j = threadIdx.x;
    if (j < 16) {
        const float invM = 1.0f / (float)MROWS;
        float w[7];
#pragma unroll
        for (int i = 0; i < 7; i++) w[i] = w1[i * 16 + j];
        float m = 0.f;
#pragma unroll
        for (int i = 0; i < 7; i++) m = fmaf(w[i], stats[i], m);
        m *= invM;
        float e2 = 0.f;
        int t = 7;
#pragma unroll
        for (int i = 0; i < 7; i++)
#pragma unroll
            for (int l = i; l < 7; l++) {
                float coeff = (i == l) ? 1.0f : 2.0f;
                e2 = fmaf(coeff * w[i] * w[l], stats[t], e2);
                t++;
            }
        e2 *= invM;
        float v = e2 - m * m;
        float sc = g[j] * rsqrtf(v + EPSB);
        scsh[j] = sc;
        scsh[16 + j] = fmaf(-m, sc, b[j]);
    }
}

// fallback z-stats, half-channel gather variant (32 accs)
template <int HALF>
__global__ __launch_bounds__(256) void k_s2h(
    const float4* __restrict__ pk, const int* __restrict__ gidx,
    const float* __restrict__ w1, const float* __restrict__ w2,
    const float* __restrict__ scsh1, float* __restrict__ stats)
{
    __shared__ __align__(16) float w1s[112];
    __shared__ __align__(16) float w2s[512];
    __shared__ float sc1s[16], sh1s[16];
    __shared__ float red[4 * 32];
    for (int i = threadIdx.x; i < 112; i += 256) w1s[i] = w1[i];
    for (int i = threadIdx.x; i < 512; i += 256) w2s[i] = w2[i];
    if (threadIdx.x < 16) {
        sc1s[threadIdx.x] = scsh1[threadIdx.x];
        sh1s[threadIdx.x] = scsh1[16 + threadIdx.x];
    }
    __syncthreads();
    const float4* w1v = (const float4*)w1s;
    const float4* w2v = (const float4*)w2s;

    float acc[32];
#pragma unroll
    for (int c = 0; c < 32; c++) acc[c] = 0.f;

    int stride = gridDim.x * 256;
#pragma unroll 1
    for (int r = blockIdx.x * 256 + threadIdx.x; r < MROWS; r += stride) {
        int n = r >> 4;
        int idx = gidx[r];
        float4 pa = pk[2 * idx];
        float4 fb = pk[2 * idx + 1];
        float4 pc = pk[2 * n];
        float x[7];
        x[0] = pa.x - pc.x; x[1] = pa.y - pc.y; x[2] = pa.z - pc.z;
        x[3] = fb.x; x[4] = fb.y; x[5] = fb.z; x[6] = fb.w;
        float h1[16];
#pragma unroll
        for (int j0 = 0; j0 < 16; j0 += 4) {
            float y0 = 0.f, y1 = 0.f, y2 = 0.f, y3 = 0.f;
#pragma unroll
            for (int i = 0; i < 7; i++) {
                float4 w = w1v[i * 4 + (j0 >> 2)];
                float xi = x[i];
                y0 = fmaf(xi, w.x, y0); y1 = fmaf(xi, w.y, y1);
                y2 = fmaf(xi, w.z, y2); y3 = fmaf(xi, w.w, y3);
            }
            h1[j0 + 0] = gelu_f(fmaf(y0, sc1s[j0 + 0], sh1s[j0 + 0]));
            h1[j0 + 1] = gelu_f(fmaf(y1, sc1s[j0 + 1], sh1s[j0 + 1]));
            h1[j0 + 2] = gelu_f(fmaf(y2, sc1s[j0 + 2], sh1s[j0 + 2]));
            h1[j0 + 3] = gelu_f(fmaf(y3, sc1s[j0 + 3], sh1s[j0 + 3]));
        }
#pragma unroll
        for (int j0 = 0; j0 < 16; j0 += 4) {
            float y0 = 0.f, y1 = 0.f, y2 = 0.f, y3 = 0.f;
#pragma unroll
            for (int i = 0; i < 16; i++) {
                float4 w = w2v[i * 8 + HALF * 4 + (j0 >> 2)];
                float hi = h1[i];
                y0 = fmaf(hi, w.x, y0); y1 = fmaf(hi, w.y, y1);
                y2 = fmaf(hi, w.z, y2); y3 = fmaf(hi, w.w, y3);
            }
            acc[j0 + 0] += y0; acc[16 + j0 + 0] += y0 * y0;
            acc[j0 + 1] += y1; acc[16 + j0 + 1] += y1 * y1;
            acc[j0 + 2] += y2; acc[16 + j0 + 2] += y2 * y2;
            acc[j0 + 3] += y3; acc[16 + j0 + 3] += y3 * y3;
        }
    }
    int lane = threadIdx.x & 63, wv = threadIdx.x >> 6;
#pragma unroll
    for (int c = 0; c < 32; c++) {
        float v = acc[c];
        v += __shfl_down(v, 32); v += __shfl_down(v, 16); v += __shfl_down(v, 8);
        v += __shfl_down(v, 4);  v += __shfl_down(v, 2);  v += __shfl_down(v, 1);
        if (lane == 0) red[wv * 32 + c] = v;
    }
    __syncthreads();
    for (int c = threadIdx.x; c < 32; c += 256) {
        float v = red[c] + red[32 + c] + red[64 + c] + red[96 + c];
        int ch = HALF * 16 + (c & 15);
        atomicAdd(&stats[(c < 16) ? ch : (32 + ch)], v);
    }
}

__global__ __launch_bounds__(256) void k_pool2g(
    const float* __restrict__ p, const float4* __restrict__ f,
    const int* __restrict__ gidx,
    const float* __restrict__ w1, const float* __restrict__ w2,
    const float* __restrict__ w3,
    const float* __restrict__ scsh1, const float* __restrict__ scsh2,
    float* __restrict__ stats, float* __restrict__ pooled)
{
    __shared__ __align__(16) float w1s[112];
    __shared__ __align__(16) float w2s[512];
    __shared__ __align__(16) float w3s[2048];
    __shared__ __align__(16) float h2t[32 * H2LD];
    __shared__ float sc1s[16], sh1s[16], sc2s[32], sh2s[32];
    __shared__ float reds[256];
    __shared__ float redq[256];
    int tid = threadIdx.x;
    for (int i = tid; i < 112; i += 256) w1s[i] = w1[i];
    for (int i = tid; i < 512; i += 256) w2s[i] = w2[i];
    for (int i = tid; i < 2048; i += 256) w3s[i] = w3[i];
    if (tid < 16) { sc1s[tid] = scsh1[tid]; sh1s[tid] = scsh1[16 + tid]; }
    if (tid < 32) { sc2s[tid] = scsh2[tid]; sh2s[tid] = scsh2[32 + tid]; }
    __syncthreads();

    const float4* w1v = (const float4*)w1s;
    const float4* w2v = (const float4*)w2s;
    const float4* w3v = (const float4*)w3s;

    int lane = tid & 63;
    int pt = tid >> 4;
    int cc = tid & 15;

    float s0 = 0.f, s1 = 0.f, s2 = 0.f, s3 = 0.f;
    float q0 = 0.f, q1 = 0.f, q2 = 0.f, q3 = 0.f;

#pragma unroll 1
    for (int it = 0; it < 4; it++) {
        int r = it * 800000 + blockIdx.x * 256 + tid;
        int n = r >> 4;
        int idx = gidx[r];
        float4 fv = f[idx];
        float x[7];
        x[0] = p[idx * 3 + 0] - p[n * 3 + 0];
        x[1] = p[idx * 3 + 1] - p[n * 3 + 1];
        x[2] = p[idx * 3 + 2] - p[n * 3 + 2];
        x[3] = fv.x; x[4] = fv.y; x[5] = fv.z; x[6] = fv.w;

        float h1[16];
#pragma unroll
        for (int j0 = 0; j0 < 16; j0 += 4) {
            float y0 = 0.f, y1 = 0.f, y2 = 0.f, y3 = 0.f;
#pragma unroll
            for (int i = 0; i < 7; i++) {
                float4 w = w1v[i * 4 + (j0 >> 2)];
                float xi = x[i];
                y0 = fmaf(xi, w.x, y0); y1 = fmaf(xi, w.y, y1);
                y2 = fmaf(xi, w.z, y2); y3 = fmaf(xi, w.w, y3);
            }
            h1[j0 + 0] = gelu_f(fmaf(y0, sc1s[j0 + 0], sh1s[j0 + 0]));
            h1[j0 + 1] = gelu_f(fmaf(y1, sc1s[j0 + 1], sh1s[j0 + 1]));
            h1[j0 + 2] = gelu_f(fmaf(y2, sc1s[j0 + 2], sh1s[j0 + 2]));
            h1[j0 + 3] = gelu_f(fmaf(y3, sc1s[j0 + 3], sh1s[j0 + 3]));
        }
#pragma unroll
        for (int j0 = 0; j0 < 32; j0 += 4) {
            float y0 = 0.f, y1 = 0.f, y2 = 0.f, y3 = 0.f;
#pragma unroll
            for (int i = 0; i < 16; i++) {
                float4 w = w2v[i * 8 + (j0 >> 2)];
                float hi = h1[i];
                y0 = fmaf(hi, w.x, y0); y1 = fmaf(hi, w.y, y1);
                y2 = fmaf(hi, w.z, y2); y3 = fmaf(hi, w.w, y3);
            }
            h2t[(j0 + 0) * H2LD + tid] = gelu_f(fmaf(y0, sc2s[j0 + 0], sh2s[j0 + 0]));
            h2t[(j0 + 1) * H2LD + tid] = gelu_f(fmaf(y1, sc2s[j0 + 1], sh2s[j0 + 1]));
            h2t[(j0 + 2) * H2LD + tid] = gelu_f(fmaf(y2, sc2s[j0 + 2], sh2s[j0 + 2]));
            h2t[(j0 + 3) * H2LD + tid] = gelu_f(fmaf(y3, sc2s[j0 + 3], sh2s[j0 + 3]));
        }
        __syncthreads();

        float a[16][4];
#pragma unroll
        for (int t = 0; t < 16; t++) {
            a[t][0] = 0.f; a[t][1] = 0.f; a[t][2] = 0.f; a[t][3] = 0.f;
        }
        int rb0 = pt << 4;
#define ACC4(t, hv) \
            a[t][0] = fmaf(hv, wf.x, a[t][0]); \
            a[t][1] = fmaf(hv, wf.y, a[t][1]); \
            a[t][2] = fmaf(hv, wf.z, a[t][2]); \
            a[t][3] = fmaf(hv, wf.w, a[t][3]);
#pragma unroll 8
        for (int i = 0; i < 32; i++) {
            float4 wf = w3v[i * 16 + cc];
            const float4* hp = (const float4*)&h2t[i * H2LD + rb0];
            float4 hA = hp[0];
            float4 hB = hp[1];
            float4 hC = hp[2];
            float4 hD = hp[3];
            ACC4(0,  hA.x) ACC4(1,  hA.y) ACC4(2,  hA.z) ACC4(3,  hA.w)
            ACC4(4,  hB.x) ACC4(5,  hB.y) ACC4(6,  hB.z) ACC4(7,  hB.w)
            ACC4(8,  hC.x) ACC4(9,  hC.y) ACC4(10, hC.z) ACC4(11, hC.w)
            ACC4(12, hD.x) ACC4(13, hD.y) ACC4(14, hD.z) ACC4(15, hD.w)
        }
#undef ACC4
        float m0 = -3.0e38f, m1 = -3.0e38f, m2 = -3.0e38f, m3 = -3.0e38f;
#pragma unroll
        for (int t = 0; t < 16; t++) {
            m0 = fmaxf(m0, a[t][0]);
            m1 = fmaxf(m1, a[t][1]);
            m2 = fmaxf(m2, a[t][2]);
            m3 = fmaxf(m3, a[t][3]);
        }
        int np = it * 50000 + blockIdx.x * 16 + pt;
        *(float4*)&pooled[(size_t)np * 64 + cc * 4] = make_float4(m0, m1, m2, m3);
        s0 += m0; q0 = fmaf(m0, m0, q0);
        s1 += m1; q1 = fmaf(m1, m1, q1);
        s2 += m2; q2 = fmaf(m2, m2, q2);
        s3 += m3; q3 = fmaf(m3, m3, q3);
        __syncthreads();
    }

    s0 += __shfl_down(s0, 32); s0 += __shfl_down(s0, 16);
    s1 += __shfl_down(s1, 32); s1 += __shfl_down(s1, 16);
    s2 += __shfl_down(s2, 32); s2 += __shfl_down(s2, 16);
    s3 += __shfl_down(s3, 32); s3 += __shfl_down(s3, 16);
    q0 += __shfl_down(q0, 32); q0 += __shfl_down(q0, 16);
    q1 += __shfl_down(q1, 32); q1 += __shfl_down(q1, 16);
    q2 += __shfl_down(q2, 32); q2 += __shfl_down(q2, 16);
    q3 += __shfl_down(q3, 32); q3 += __shfl_down(q3, 16);
    int wv = tid >> 6;
    if (lane < 16) {
        reds[wv * 64 + lane * 4 + 0] = s0;
        reds[wv * 64 + lane * 4 + 1] = s1;
        reds[wv * 64 + lane * 4 + 2] = s2;
        reds[wv * 64 + lane * 4 + 3] = s3;
        redq[wv * 64 + lane * 4 + 0] = q0;
        redq[wv * 64 + lane * 4 + 1] = q1;
        redq[wv * 64 + lane * 4 + 2] = q2;
        redq[wv * 64 + lane * 4 + 3] = q3;
    }
    __syncthreads();
    if (tid < 64) {
        atomicAdd(&stats[tid],
                  reds[tid] + reds[64 + tid] + reds[128 + tid] + reds[192 + tid]);
        atomicAdd(&stats[64 + tid],
                  redq[tid] + redq[64 + tid] + redq[128 + tid] + redq[192 + tid]);
    }
}

// double-BN collapse
__global__ void k_fin3(const float* __restrict__ stats,
                       const float* __restrict__ g_nbr, const float* __restrict__ g_post,
                       const float* __restrict__ b_post, float* __restrict__ scsh)
{
    int j = threadIdx.x;
    if (j < 64) {
        float m = stats[j] * (1.0f / NPTS);
        float v = stats[64 + j] * (1.0f / NPTS) - m * m;
        float a1 = g_nbr[j] * rsqrtf(v + EPSB);
        float s3 = g_post[j] * a1 * rsqrtf(fmaf(a1 * a1, v, EPSB));
        scsh[j] = s3;
        scsh[64 + j] = fmaf(-m, s3, b_post[j]);
    }
}

// head: (N x 64) @ (64 x 256)
__global__ __launch_bounds__(256) void k_head(
    const float* __restrict__ pooled, const float* __restrict__ scsh3,
    const float* __restrict__ wpost, float* __restrict__ out)
{
    __shared__ float rowbuf[512];
    __shared__ float s3s[64], c3s[64];
    int tid = threadIdx.x;
    if (tid < 64) { s3s[tid] = scsh3[tid]; c3s[tid] = scsh3[64 + tid]; }
    float wcol[64];
#pragma unroll
    for (int j = 0; j < 64; j++) wcol[j] = wpost[j * 256 + tid];
    __syncthreads();

    const int nchunks = NPTS / 8;  // 25000
    for (int c = blockIdx.x; c < nchunks; c += gridDim.x) {
        int n0 = c * 8;
#pragma unroll
        for (int t = tid; t < 512; t += 256) {
            int rr = t >> 6, j = t & 63;
            rowbuf[t] = fmaf(pooled[(size_t)(n0 + rr) * 64 + j], s3s[j], c3s[j]);
        }
        __syncthreads();
#pragma unroll
        for (int rr = 0; rr < 8; rr++) {
            float acc = 0.f;
#pragma unroll
            for (int j = 0; j < 64; j++) acc = fmaf(rowbuf[rr * 64 + j], wcol[j], acc);
            out[(size_t)(n0 + rr) * 256 + tid] = acc;
        }
        __syncthreads();
    }
}

extern "C" void kernel_launch(void* const* d_in, const int* in_sizes, int n_in,
                              void* d_out, int out_size, void* d_ws, size_t ws_size,
                              hipStream_t stream)
{
    const float*  p    = (const float*)d_in[0];
    const float4* f    = (const float4*)d_in[1];
    const int*    gidx = (const int*)d_in[2];
    const float*  w1   = (const float*)d_in[3];
    const float*  g1   = (const float*)d_in[4];
    const float*  b1   = (const float*)d_in[5];
    const float*  w2   = (const float*)d_in[6];
    const float*  g2   = (const float*)d_in[7];
    const float*  b2   = (const float*)d_in[8];
    const float*  w3   = (const float*)d_in[9];
    const float*  gn   = (const float*)d_in[10];
    // d_in[11] = b_nbr: cancels exactly in the collapsed double-BN
    const float*  gp   = (const float*)d_in[12];
    const float*  bp   = (const float*)d_in[13];
    const float*  wp   = (const float*)d_in[14];
    float* out = (float*)d_out;
    float* ws  = (float*)d_ws;

    float* stats1 = ws;          // 35 floats max
    float* scsh1  = ws + 40;     // 32
    float* stats2 = ws + 80;     // 64 floats (sum32 + sumsq32)
    float* scsh2  = ws + 240;    // 64
    float* stats3 = ws + 304;    // 128
    float* scsh3  = ws + 432;    // 128
    float* pooled = ws + 1024;               // 12.8M floats (51.2 MB)
    float4* pk    = (float4*)(ws + 1024);    // aliases pooled (dead before pool writes)
    float* y1d    = ws + 1024 + 12800000;    // 51.2M floats (204.8 MB)

    const size_t need = ((size_t)1024 + 12800000 + 51200000) * 4;

    hipMemsetAsync(d_ws, 0, 2048, stream);
    k_pack<<<(NPTS + 255) / 256, 256, 0, stream>>>(p, f, pk);

    if (ws_size >= need) {
        k_gy1<<<2048, 256, 0, stream>>>(pk, gidx, w1, stats1, y1d);
        k_fin1b<<<1, 64, 0, stream>>>(stats1, g1, b1, scsh1);
        k_momZh<0><<<3125, 256, 0, stream>>>(y1d, w2, scsh1, stats2);
        k_momZh<1><<<3125, 256, 0, stream>>>(y1d, w2, scsh1, stats2);
        k_finalize<<<1, 64, 0, stream>>>(stats2, g2, b2, scsh2, 32, 1.0f / (float)MROWS);
        k_pool2y<<<3125, 256, 0, stream>>>(y1d, w2, w3, scsh1, scsh2, stats3, pooled);
    } else {
        k_s1g<<<2048, 256, 0, stream>>>(pk, gidx, stats1);
        k_f1g<<<1, 64, 0, stream>>>(stats1, w1, g1, b1, scsh1);
        k_s2h<0><<<2048, 256, 0, stream>>>(pk, gidx, w1, w2, scsh1, stats2);
        k_s2h<1><<<2048, 256, 0, stream>>>(pk, gidx, w1, w2, scsh1, stats2);
        k_finalize<<<1, 64, 0, stream>>>(stats2, g2, b2, scsh2, 32, 1.0f / (float)MROWS);
        k_pool2g<<<3125, 256, 0, stream>>>(p, f, gidx, w1, w2, w3, scsh1, scsh2, stats3, pooled);
    }
    k_fin3<<<1, 64, 0, stream>>>(stats3, gn, gp, bp, scsh3);
    k_head<<<1024, 256, 0, stream>>>(pooled, scsh3, wp, out);
}